// Round 6
// baseline (450.388 us; speedup 1.0000x reference)
//
#include <hip/hip_runtime.h>
#include <stdint.h>
#include <stddef.h>

typedef _Float16 f16;
typedef __attribute__((ext_vector_type(8))) _Float16 f16x8;
typedef __attribute__((ext_vector_type(4))) _Float16 f16x4;
typedef __attribute__((ext_vector_type(4))) float f32x4;
typedef __attribute__((ext_vector_type(2))) float f32x2;

#define L_SEQ 16384
#define DH    1024
#define DM    1024
#define NH2   2048           // 2*DH, interleaved complex width
#define NC    512            // chunks (R5: 256->512 for scan parallelism)
#define LC    (L_SEQ / NC)   // 32

// W/Bu/scan domain scaled by 64 to keep tiny B*e^gamma rows (near-unit-|lambda|
// channels, ~2e-5) out of fp16 subnormal range. Unscaled at the two exits.
#define WSCALE     64.0f
#define INV_WSCALE 0.015625f

__device__ __forceinline__ void async_copy16(const void* g, void* l) {
  __builtin_amdgcn_global_load_lds((const __attribute__((address_space(1))) void*)g,
                                   (__attribute__((address_space(3))) void*)l,
                                   16, 0, 0);
}

__device__ __forceinline__ float h_lo(uint32_t w) {
  uint16_t u = (uint16_t)(w & 0xffffu); f16 h; __builtin_memcpy(&h, &u, 2); return (float)h;
}
__device__ __forceinline__ float h_hi(uint32_t w) {
  uint16_t u = (uint16_t)(w >> 16); f16 h; __builtin_memcpy(&h, &u, 2); return (float)h;
}

// ---------------- fused prep ----------------
// Interleaved complex layout everywhere: channel h -> cols/rows (2h, 2h+1).
#define NB_CAST 8192
#define NB_W    1024
__global__ void k_prep_all(const float* __restrict__ x, f16* __restrict__ xb,
                           const float* __restrict__ B_re, const float* __restrict__ B_im,
                           const float* __restrict__ gamma_log, f16* __restrict__ Wcat,
                           const float* __restrict__ C_re, const float* __restrict__ C_im,
                           f16* __restrict__ Ccat,
                           const float* __restrict__ nu_log,
                           const float* __restrict__ theta_log,
                           float* __restrict__ lam_re, float* __restrict__ lam_im,
                           float* __restrict__ lamC_re, float* __restrict__ lamC_im) {
  const int b = blockIdx.x;
  if (b < NB_CAST) {
    int i = (b * 256 + (int)threadIdx.x) * 8;
    const float4 a0 = *(const float4*)(x + i);
    const float4 a1 = *(const float4*)(x + i + 4);
    f16x8 v;
    v[0] = (f16)a0.x; v[1] = (f16)a0.y; v[2] = (f16)a0.z; v[3] = (f16)a0.w;
    v[4] = (f16)a1.x; v[5] = (f16)a1.y; v[6] = (f16)a1.z; v[7] = (f16)a1.w;
    *(f16x8*)(xb + i) = v;
  } else if (b < NB_CAST + NB_W) {
    int idx = ((b - NB_CAST) * 256 + (int)threadIdx.x) * 4;  // over H*DM
    int h = idx / DM;
    int d = idx - h * DM;
    float g = expf(gamma_log[h]) * WSCALE;
    float4 re = *(const float4*)(B_re + idx);
    float4 im = *(const float4*)(B_im + idx);
    f16x4 vr, vi;
    vr[0] = (f16)(re.x * g); vr[1] = (f16)(re.y * g);
    vr[2] = (f16)(re.z * g); vr[3] = (f16)(re.w * g);
    vi[0] = (f16)(im.x * g); vi[1] = (f16)(im.y * g);
    vi[2] = (f16)(im.z * g); vi[3] = (f16)(im.w * g);
    *(f16x4*)(Wcat + (size_t)(2 * h) * DM + d)     = vr;
    *(f16x4*)(Wcat + (size_t)(2 * h + 1) * DM + d) = vi;
  } else if (b < NB_CAST + 2 * NB_W) {
    int idx = ((b - NB_CAST - NB_W) * 256 + (int)threadIdx.x) * 4;  // over DM*DH
    int d = idx / DH;
    int k = idx - d * DH;       // k multiple of 4
    float4 re = *(const float4*)(C_re + idx);
    float4 im = *(const float4*)(C_im + idx);
    f16x8 v;
    v[0] = (f16)re.x; v[1] = (f16)(-im.x);
    v[2] = (f16)re.y; v[3] = (f16)(-im.y);
    v[4] = (f16)re.z; v[5] = (f16)(-im.z);
    v[6] = (f16)re.w; v[7] = (f16)(-im.w);
    *(f16x8*)(Ccat + (size_t)d * NH2 + 2 * k) = v;
  } else {
    int h = (b - NB_CAST - 2 * NB_W) * 256 + (int)threadIdx.x;
    if (h < DH) {
      float nu  = expf(nu_log[h]);
      float th  = expf(theta_log[h]);
      float mag = expf(-nu);
      float lr = mag * cosf(th);
      float li = mag * sinf(th);
      lam_re[h] = lr; lam_im[h] = li;
      float ar = lr, ai = li;       // lambda^32 (LC=32) by repeated squaring
#pragma unroll
      for (int i = 0; i < 5; ++i) {
        float nr = ar * ar - ai * ai;
        float ni = 2.f * ar * ai;
        ar = nr; ai = ni;
      }
      lamC_re[h] = ar; lamC_im[h] = ai;
    }
  }
}

// ---------------- GEMM: C = A[M,K] * B[N,K]^T, f16 in, f32 acc ----------------
// PROVEN 128x128 core. K-loop LDS XOR-swizzle (bank-conflict-free). Supertile
// raster. launch_bounds(256,5): VGPR=64, LDS=32K -> 5 blocks/CU (160K LDS),
// was capped at 3; cross-block TLP absorbs the per-block barrier-drain stall.
// MODE 0 (GEMM1): epilogue = LDS transpose tile -> coalesced f16x8 Bu stores
//                 + per-chunk local lambda-scan -> chunk_carry (LC=32, 4/tile).
// MODE 1 (GEMM2): f32 stores + dp[col]*xb[row,col], xb = f16 Xb.
template <int MODE>
__global__ __launch_bounds__(256, 5)
void k_gemm(const f16* __restrict__ A, const f16* __restrict__ B,
            void* __restrict__ Cout, const void* __restrict__ x,
            const float* __restrict__ dp,
            const float* __restrict__ lam_re, const float* __restrict__ lam_im,
            float* __restrict__ chunk_carry, int K, int N) {
  __shared__ char smem[32768];
  f16* As = (f16*)smem;              // [128][64]
  f16* Bs = (f16*)(smem + 16384);    // [128][64]
  const int tid  = threadIdx.x;
  const int lane = tid & 63;
  const int wave = tid >> 6;
  const int wm = wave >> 1, wn = wave & 1;
  const int quad = lane >> 4;
  const int l16  = lane & 15;

  // supertile rasterization: 8 consecutive m-tiles share the window with all n-tiles
  const int lin = blockIdx.y * gridDim.x + blockIdx.x;
  const int nY  = gridDim.y;
  const int per = 8 * nY;
  const int sg  = lin / per;
  const int r   = lin - sg * per;
  const int bx  = sg * 8 + (r & 7);
  const int by  = r >> 3;
  const int m0 = bx * 128;
  const int n0 = by * 128;

  f32x4 acc[4][4];
#pragma unroll
  for (int i = 0; i < 4; ++i)
#pragma unroll
    for (int j = 0; j < 4; ++j)
      acc[i][j] = f32x4{0.f, 0.f, 0.f, 0.f};

  for (int k0 = 0; k0 < K; k0 += 64) {
    __syncthreads();
#pragma unroll
    for (int q = 0; q < 4; ++q) {
      const int c = q * 256 + tid;           // LDS 16B chunk id (lane-contiguous)
      const int row = c >> 3, slot = c & 7;
      const int part = slot ^ (row & 7);     // swizzled global source part
      async_copy16(A + (size_t)(m0 + row) * K + k0 + part * 8, (char*)As + c * 16);
      async_copy16(B + (size_t)(n0 + row) * K + k0 + part * 8, (char*)Bs + c * 16);
    }
    __syncthreads();
#pragma unroll
    for (int kk = 0; kk < 64; kk += 32) {
      const int pbase = (kk >> 3);           // 0 or 4
      f16x8 fa[4], fb[4];
#pragma unroll
      for (int i = 0; i < 4; ++i) {
        const int ra = wm * 64 + i * 16 + l16;
        const int rb = wn * 64 + i * 16 + l16;
        const int sa = (pbase + quad) ^ (ra & 7);
        const int sb = (pbase + quad) ^ (rb & 7);
        fa[i] = *(const f16x8*)(As + ra * 64 + sa * 8);
        fb[i] = *(const f16x8*)(Bs + rb * 64 + sb * 8);
      }
#pragma unroll
      for (int i = 0; i < 4; ++i)
#pragma unroll
        for (int j = 0; j < 4; ++j)
          acc[i][j] = __builtin_amdgcn_mfma_f32_16x16x32_f16(fa[i], fb[j], acc[i][j], 0, 0, 0);
    }
  }

  if (MODE == 0) {
    // ---- epilogue: tile -> LDS (col-group XOR swizzle), coalesced store + scan ----
    __syncthreads();                       // MFMA LDS reads complete
    f16* T = (f16*)smem;                   // [128][128] f16, grp = col>>3 swizzled by row&7
#pragma unroll
    for (int i = 0; i < 4; ++i)
#pragma unroll
      for (int j = 0; j < 4; ++j) {
        const int col = wn * 64 + j * 16 + l16;
        const int grp = col >> 3, cin = col & 7;
#pragma unroll
        for (int p = 0; p < 4; ++p) {
          const int row = wm * 64 + i * 16 + quad * 4 + p;
          T[row * 128 + ((grp ^ (row & 7)) << 3) + cin] = (f16)acc[i][j][p];
        }
      }
    __syncthreads();
    // coalesced Bu store: 2 threads/row, 64 cols each
    f16* out = (f16*)Cout;
    {
      const int row = tid >> 1, half = tid & 1;
#pragma unroll
      for (int o = 0; o < 8; ++o) {
        const int grp = half * 8 + o;
        f16x8 v = *(const f16x8*)(T + row * 128 + ((grp ^ (row & 7)) << 3));
        *(f16x8*)(out + (size_t)(m0 + row) * N + n0 + grp * 8) = v;
      }
    }
    // local chunk scan: all 256 threads -> (chunk ck 0..3 of 32 rows) x (ch 0..63)
    {
      const int ck = tid >> 6;
      const int ch = tid & 63;              // local complex channel
      const int gch = (n0 >> 1) + ch;       // global complex channel
      const float lr = lam_re[gch], li = lam_im[gch];
      float hr = 0.f, hi = 0.f;
#pragma unroll 8
      for (int t = 0; t < LC; ++t) {
        const int row = ck * LC + t;
        // complex pair (cols 2ch,2ch+1) lives in one 4B word; apply grp swizzle
        const int grpsw = ((ch >> 2) ^ (row & 7)) << 3;
        uint32_t w = *(const uint32_t*)(T + row * 128 + grpsw + ((2 * ch) & 7));
        float br = h_lo(w), bi = h_hi(w);
        float nr = lr * hr - li * hi + br;
        float ni = lr * hi + li * hr + bi;
        hr = nr; hi = ni;
      }
      *(f32x2*)(chunk_carry + (size_t)(4 * bx + ck) * NH2 + n0 + 2 * ch) = f32x2{hr, hi};
    }
  } else {
    float* out = (float*)Cout;
    const f16* xb = (const f16*)x;         // Xb (f16), halves D-term fetch
    const int crow0 = m0 + wm * 64 + quad * 4;
    const int ccol0 = n0 + wn * 64 + l16;
#pragma unroll
    for (int j = 0; j < 4; ++j) {
      const int col = ccol0 + j * 16;
      const float dpv = dp[col];
#pragma unroll
      for (int i = 0; i < 4; ++i)
#pragma unroll
        for (int p = 0; p < 4; ++p) {
          const int row = crow0 + i * 16 + p;
          out[(size_t)row * N + col] = acc[i][j][p] + dpv * (float)xb[(size_t)row * N + col];
        }
    }
  }
}

// ---------------- carry scan over chunks: PARALLEL Kogge-Stone, IN PLACE ------
// h_c = lamC * h_{c-1} + e_c (first-order linear recurrence over NC=512 chunks).
// Kogge-Stone: val[c] += lamC^s * val[c-s], s = 1..256 (9 LDS steps); span
// multiplier by repeated squaring. Grid: DH blocks x NC threads. In place:
// block h reads column 2h of chunk_carry (endpoints) then overwrites the same
// column with the EXCLUSIVE carries — no cross-block column sharing.
__global__ void k_scan_carry(float* __restrict__ chunk_carry,
                             const float* __restrict__ lamC_re,
                             const float* __restrict__ lamC_im,
                             float* __restrict__ out_final,
                             int interleave) {
  __shared__ float sr[NC], si[NC];
  const int h = blockIdx.x;            // complex channel 0..1023
  const int c = threadIdx.x;           // chunk 0..511
  f32x2 e = *(const f32x2*)(chunk_carry + (size_t)c * NH2 + 2 * h);
  float vr = e[0], vi = e[1];
  float pr = lamC_re[h], pi = lamC_im[h];   // lamC^(2^s)
#pragma unroll
  for (int s = 1; s < NC; s <<= 1) {
    sr[c] = vr; si[c] = vi;
    __syncthreads();
    if (c >= s) {
      const float ar = sr[c - s], ai = si[c - s];
      vr += pr * ar - pi * ai;
      vi += pr * ai + pi * ar;
    }
    __syncthreads();
    const float nr = pr * pr - pi * pi;
    const float ni = 2.f * pr * pi;
    pr = nr; pi = ni;
  }
  sr[c] = vr; si[c] = vi;
  __syncthreads();
  const float er = (c == 0) ? 0.f : sr[c - 1];
  const float ei = (c == 0) ? 0.f : si[c - 1];
  *(f32x2*)(chunk_carry + (size_t)c * NH2 + 2 * h) = f32x2{er, ei};
  if (c == NC - 1) {
    if (interleave) {
      *(f32x2*)(out_final + 2 * h) = f32x2{vr * INV_WSCALE, vi * INV_WSCALE};
    } else {
      out_final[h] = vr * INV_WSCALE;
    }
  }
}

// ---------------- apply: H over Bu in place (interleaved complex) ----------------
// Recurrence runs in the SCALED domain; stores unscale (x1/64) so H feeds GEMM2.
// LC=32: 1024 blocks (4/CU), 32-iter dependent chain.
__global__ void k_scan_apply(f16* __restrict__ Bu,
                             const float* __restrict__ lam_re,
                             const float* __restrict__ lam_im,
                             const float* __restrict__ carry_in) {
  const int colbase = (blockIdx.y * 256 + (int)threadIdx.x) * 4;  // 2 complex channels
  const int c = blockIdx.x;
  const int h0 = colbase >> 1;
  const float lr0 = lam_re[h0],     li0 = lam_im[h0];
  const float lr1 = lam_re[h0 + 1], li1 = lam_im[h0 + 1];
  f32x4 cv = *(const f32x4*)(carry_in + (size_t)c * NH2 + colbase);
  float hr0 = cv[0], hi0 = cv[1], hr1 = cv[2], hi1 = cv[3];
  f16* p = Bu + (size_t)c * LC * NH2 + colbase;
#pragma unroll 4
  for (int t = 0; t < LC; ++t) {
    f16x4 b = *(const f16x4*)(p);
    float nr0 = lr0 * hr0 - li0 * hi0 + (float)b[0];
    float ni0 = lr0 * hi0 + li0 * hr0 + (float)b[1];
    float nr1 = lr1 * hr1 - li1 * hi1 + (float)b[2];
    float ni1 = lr1 * hi1 + li1 * hr1 + (float)b[3];
    hr0 = nr0; hi0 = ni0; hr1 = nr1; hi1 = ni1;
    f16x4 wv;
    wv[0] = (f16)(hr0 * INV_WSCALE); wv[1] = (f16)(hi0 * INV_WSCALE);
    wv[2] = (f16)(hr1 * INV_WSCALE); wv[3] = (f16)(hi1 * INV_WSCALE);
    *(f16x4*)(p) = wv;
    p += NH2;
  }
}

// ---------------- launcher ----------------

extern "C" void kernel_launch(void* const* d_in, const int* in_sizes, int n_in,
                              void* d_out, int out_size, void* d_ws, size_t ws_size,
                              hipStream_t stream) {
  const float* inputs    = (const float*)d_in[0];
  const float* nu_log    = (const float*)d_in[1];
  const float* theta_log = (const float*)d_in[2];
  const float* gamma_log = (const float*)d_in[3];
  const float* B_re      = (const float*)d_in[4];
  const float* B_im      = (const float*)d_in[5];
  const float* C_re      = (const float*)d_in[6];
  const float* C_im      = (const float*)d_in[7];
  const float* Dp        = (const float*)d_in[8];

  char* ws = (char*)d_ws;
  float* lam_re     = (float*)(ws + 0);
  float* lam_im     = (float*)(ws + 4096);
  float* lamC_re    = (float*)(ws + 8192);
  float* lamC_im    = (float*)(ws + 12288);
  float* chunk_carry= (float*)(ws + 65536);                    //  4 MB [NC][NH2]
  f16*   Wcat       = (f16*)  (ws + 65536 + (4u << 20));       //  4 MB
  f16*   Ccat       = (f16*)  (ws + 65536 + (8u << 20));       //  4 MB
  f16*   Xb         = (f16*)  (ws + 65536 + (12u << 20));      // 32 MB
  f16*   Bu         = (f16*)  (ws + 65536 + (44u << 20));      // 64 MB (H in place)

  int interleave = 1;
  int state_floats = 2048;
  if (out_size == 1024 + L_SEQ * DM) { interleave = 0; state_floats = 1024; }

  float* out_state = (float*)d_out;
  float* out_y     = (float*)d_out + state_floats;   // [L, DM] f32

  k_prep_all<<<dim3(NB_CAST + 2 * NB_W + 4), dim3(256), 0, stream>>>(
      inputs, Xb, B_re, B_im, gamma_log, Wcat, C_re, C_im, Ccat,
      nu_log, theta_log, lam_re, lam_im, lamC_re, lamC_im);

  // GEMM1: Bu[L, NH2] = Xb[L, DM] @ Wcat[NH2, DM]^T, + local chunk scan -> chunk_carry
  k_gemm<0><<<dim3(L_SEQ / 128, NH2 / 128), dim3(256), 0, stream>>>(
      Xb, Wcat, (void*)Bu, nullptr, nullptr, lam_re, lam_im, chunk_carry, DM, NH2);

  // carry scan in place: endpoints -> exclusive carries (+ final state out)
  k_scan_carry<<<dim3(DH), dim3(NC), 0, stream>>>(chunk_carry, lamC_re, lamC_im,
                                                  out_state, interleave);
  k_scan_apply<<<dim3(NC, 2), dim3(256), 0, stream>>>(Bu, lam_re, lam_im, chunk_carry);

  // GEMM2: out_y = H[L, NH2] @ Ccat[DM, NH2]^T + Dp*Xb  (Xb passed as x, f16)
  k_gemm<1><<<dim3(L_SEQ / 128, DM / 128), dim3(256), 0, stream>>>(
      Bu, Ccat, (void*)out_y, Xb, Dp, nullptr, nullptr, nullptr, NH2, DM);

  (void)in_sizes; (void)n_in; (void)ws_size;
}

// Round 7
// 334.555 us; speedup vs baseline: 1.3462x; 1.3462x over previous
//
#include <hip/hip_runtime.h>
#include <stdint.h>
#include <stddef.h>

typedef _Float16 f16;
typedef __attribute__((ext_vector_type(8))) _Float16 f16x8;
typedef __attribute__((ext_vector_type(4))) _Float16 f16x4;
typedef __attribute__((ext_vector_type(4))) float f32x4;
typedef __attribute__((ext_vector_type(2))) float f32x2;

#define L_SEQ 16384
#define DH    1024
#define DM    1024
#define NH2   2048           // 2*DH, interleaved complex width
#define NC    512            // chunks (512 -> LC=32 scan chain, better absmax)
#define LC    (L_SEQ / NC)   // 32

// W/Bu/scan domain scaled by 64 to keep tiny B*e^gamma rows (near-unit-|lambda|
// channels, ~2e-5) out of fp16 subnormal range. Unscaled at the two exits.
#define WSCALE     64.0f
#define INV_WSCALE 0.015625f

__device__ __forceinline__ void async_copy16(const void* g, void* l) {
  __builtin_amdgcn_global_load_lds((const __attribute__((address_space(1))) void*)g,
                                   (__attribute__((address_space(3))) void*)l,
                                   16, 0, 0);
}

__device__ __forceinline__ float h_lo(uint32_t w) {
  uint16_t u = (uint16_t)(w & 0xffffu); f16 h; __builtin_memcpy(&h, &u, 2); return (float)h;
}
__device__ __forceinline__ float h_hi(uint32_t w) {
  uint16_t u = (uint16_t)(w >> 16); f16 h; __builtin_memcpy(&h, &u, 2); return (float)h;
}

// ---------------- fused prep ----------------
// Interleaved complex layout everywhere: channel h -> cols/rows (2h, 2h+1).
#define NB_CAST 8192
#define NB_W    1024
__global__ void k_prep_all(const float* __restrict__ x, f16* __restrict__ xb,
                           const float* __restrict__ B_re, const float* __restrict__ B_im,
                           const float* __restrict__ gamma_log, f16* __restrict__ Wcat,
                           const float* __restrict__ C_re, const float* __restrict__ C_im,
                           f16* __restrict__ Ccat,
                           const float* __restrict__ nu_log,
                           const float* __restrict__ theta_log,
                           float* __restrict__ lam_re, float* __restrict__ lam_im,
                           float* __restrict__ lamC_re, float* __restrict__ lamC_im) {
  const int b = blockIdx.x;
  if (b < NB_CAST) {
    int i = (b * 256 + (int)threadIdx.x) * 8;
    const float4 a0 = *(const float4*)(x + i);
    const float4 a1 = *(const float4*)(x + i + 4);
    f16x8 v;
    v[0] = (f16)a0.x; v[1] = (f16)a0.y; v[2] = (f16)a0.z; v[3] = (f16)a0.w;
    v[4] = (f16)a1.x; v[5] = (f16)a1.y; v[6] = (f16)a1.z; v[7] = (f16)a1.w;
    *(f16x8*)(xb + i) = v;
  } else if (b < NB_CAST + NB_W) {
    int idx = ((b - NB_CAST) * 256 + (int)threadIdx.x) * 4;  // over H*DM
    int h = idx / DM;
    int d = idx - h * DM;
    float g = expf(gamma_log[h]) * WSCALE;
    float4 re = *(const float4*)(B_re + idx);
    float4 im = *(const float4*)(B_im + idx);
    f16x4 vr, vi;
    vr[0] = (f16)(re.x * g); vr[1] = (f16)(re.y * g);
    vr[2] = (f16)(re.z * g); vr[3] = (f16)(re.w * g);
    vi[0] = (f16)(im.x * g); vi[1] = (f16)(im.y * g);
    vi[2] = (f16)(im.z * g); vi[3] = (f16)(im.w * g);
    *(f16x4*)(Wcat + (size_t)(2 * h) * DM + d)     = vr;
    *(f16x4*)(Wcat + (size_t)(2 * h + 1) * DM + d) = vi;
  } else if (b < NB_CAST + 2 * NB_W) {
    int idx = ((b - NB_CAST - NB_W) * 256 + (int)threadIdx.x) * 4;  // over DM*DH
    int d = idx / DH;
    int k = idx - d * DH;       // k multiple of 4
    float4 re = *(const float4*)(C_re + idx);
    float4 im = *(const float4*)(C_im + idx);
    f16x8 v;
    v[0] = (f16)re.x; v[1] = (f16)(-im.x);
    v[2] = (f16)re.y; v[3] = (f16)(-im.y);
    v[4] = (f16)re.z; v[5] = (f16)(-im.z);
    v[6] = (f16)re.w; v[7] = (f16)(-im.w);
    *(f16x8*)(Ccat + (size_t)d * NH2 + 2 * k) = v;
  } else {
    int h = (b - NB_CAST - 2 * NB_W) * 256 + (int)threadIdx.x;
    if (h < DH) {
      float nu  = expf(nu_log[h]);
      float th  = expf(theta_log[h]);
      float mag = expf(-nu);
      float lr = mag * cosf(th);
      float li = mag * sinf(th);
      lam_re[h] = lr; lam_im[h] = li;
      float ar = lr, ai = li;       // lambda^32 (LC=32) by repeated squaring
#pragma unroll
      for (int i = 0; i < 5; ++i) {
        float nr = ar * ar - ai * ai;
        float ni = 2.f * ar * ai;
        ar = nr; ai = ni;
      }
      lamC_re[h] = ar; lamC_im[h] = ai;
    }
  }
}

// ---------------- GEMM: C = A[M,K] * B[N,K]^T, f16 in, f32 acc ----------------
// PROVEN 128x128 core @ 3 blocks/CU (R6 measured: 5/CU doubles HBM traffic via
// L2 thrash — keep 3). K-loop LDS XOR-swizzle (bank-conflict-free). Bijective
// XCD swizzle (T1) + supertile raster: contiguous windows pinned per XCD-L2.
// MODE 0 (GEMM1): epilogue = LDS transpose tile -> coalesced f16x8 Bu stores
//                 + per-chunk local lambda-scan -> chunk_carry (LC=32, 4/tile).
// MODE 1 (GEMM2): f32 stores + dp[col]*xb[row,col], xb = f16 Xb.
template <int MODE>
__global__ __launch_bounds__(256, 3)
void k_gemm(const f16* __restrict__ A, const f16* __restrict__ B,
            void* __restrict__ Cout, const void* __restrict__ x,
            const float* __restrict__ dp,
            const float* __restrict__ lam_re, const float* __restrict__ lam_im,
            float* __restrict__ chunk_carry, int K, int N) {
  __shared__ char smem[32768];
  f16* As = (f16*)smem;              // [128][64]
  f16* Bs = (f16*)(smem + 16384);    // [128][64]
  const int tid  = threadIdx.x;
  const int lane = tid & 63;
  const int wave = tid >> 6;
  const int wm = wave >> 1, wn = wave & 1;
  const int quad = lane >> 4;
  const int l16  = lane & 15;

  // bijective XCD swizzle (nwg % 8 == 0), then supertile raster:
  // 8 consecutive m-tiles share the window with all n-tiles.
  const int lin0 = blockIdx.y * gridDim.x + blockIdx.x;
  const int nwg  = gridDim.x * gridDim.y;
  const int lin  = (lin0 & 7) * (nwg >> 3) + (lin0 >> 3);
  const int nY  = gridDim.y;
  const int per = 8 * nY;
  const int sg  = lin / per;
  const int r   = lin - sg * per;
  const int bx  = sg * 8 + (r & 7);
  const int by  = r >> 3;
  const int m0 = bx * 128;
  const int n0 = by * 128;

  f32x4 acc[4][4];
#pragma unroll
  for (int i = 0; i < 4; ++i)
#pragma unroll
    for (int j = 0; j < 4; ++j)
      acc[i][j] = f32x4{0.f, 0.f, 0.f, 0.f};

  for (int k0 = 0; k0 < K; k0 += 64) {
    __syncthreads();
#pragma unroll
    for (int q = 0; q < 4; ++q) {
      const int c = q * 256 + tid;           // LDS 16B chunk id (lane-contiguous)
      const int row = c >> 3, slot = c & 7;
      const int part = slot ^ (row & 7);     // swizzled global source part
      async_copy16(A + (size_t)(m0 + row) * K + k0 + part * 8, (char*)As + c * 16);
      async_copy16(B + (size_t)(n0 + row) * K + k0 + part * 8, (char*)Bs + c * 16);
    }
    __syncthreads();
#pragma unroll
    for (int kk = 0; kk < 64; kk += 32) {
      const int pbase = (kk >> 3);           // 0 or 4
      f16x8 fa[4], fb[4];
#pragma unroll
      for (int i = 0; i < 4; ++i) {
        const int ra = wm * 64 + i * 16 + l16;
        const int rb = wn * 64 + i * 16 + l16;
        const int sa = (pbase + quad) ^ (ra & 7);
        const int sb = (pbase + quad) ^ (rb & 7);
        fa[i] = *(const f16x8*)(As + ra * 64 + sa * 8);
        fb[i] = *(const f16x8*)(Bs + rb * 64 + sb * 8);
      }
#pragma unroll
      for (int i = 0; i < 4; ++i)
#pragma unroll
        for (int j = 0; j < 4; ++j)
          acc[i][j] = __builtin_amdgcn_mfma_f32_16x16x32_f16(fa[i], fb[j], acc[i][j], 0, 0, 0);
    }
  }

  if (MODE == 0) {
    // ---- epilogue: tile -> LDS (col-group XOR swizzle), coalesced store + scan ----
    __syncthreads();                       // MFMA LDS reads complete
    f16* T = (f16*)smem;                   // [128][128] f16, grp = col>>3 swizzled by row&7
#pragma unroll
    for (int i = 0; i < 4; ++i)
#pragma unroll
      for (int j = 0; j < 4; ++j) {
        const int col = wn * 64 + j * 16 + l16;
        const int grp = col >> 3, cin = col & 7;
#pragma unroll
        for (int p = 0; p < 4; ++p) {
          const int row = wm * 64 + i * 16 + quad * 4 + p;
          T[row * 128 + ((grp ^ (row & 7)) << 3) + cin] = (f16)acc[i][j][p];
        }
      }
    __syncthreads();
    // coalesced Bu store: 2 threads/row, 64 cols each
    f16* out = (f16*)Cout;
    {
      const int row = tid >> 1, half = tid & 1;
#pragma unroll
      for (int o = 0; o < 8; ++o) {
        const int grp = half * 8 + o;
        f16x8 v = *(const f16x8*)(T + row * 128 + ((grp ^ (row & 7)) << 3));
        *(f16x8*)(out + (size_t)(m0 + row) * N + n0 + grp * 8) = v;
      }
    }
    // local chunk scan: all 256 threads -> (chunk ck 0..3 of 32 rows) x (ch 0..63)
    {
      const int ck = tid >> 6;
      const int ch = tid & 63;              // local complex channel
      const int gch = (n0 >> 1) + ch;       // global complex channel
      const float lr = lam_re[gch], li = lam_im[gch];
      float hr = 0.f, hi = 0.f;
#pragma unroll 8
      for (int t = 0; t < LC; ++t) {
        const int row = ck * LC + t;
        // complex pair (cols 2ch,2ch+1) lives in one 4B word; apply grp swizzle
        const int grpsw = ((ch >> 2) ^ (row & 7)) << 3;
        uint32_t w = *(const uint32_t*)(T + row * 128 + grpsw + ((2 * ch) & 7));
        float br = h_lo(w), bi = h_hi(w);
        float nr = lr * hr - li * hi + br;
        float ni = lr * hi + li * hr + bi;
        hr = nr; hi = ni;
      }
      *(f32x2*)(chunk_carry + (size_t)(4 * bx + ck) * NH2 + n0 + 2 * ch) = f32x2{hr, hi};
    }
  } else {
    float* out = (float*)Cout;
    const f16* xb = (const f16*)x;         // Xb (f16), halves D-term fetch
    const int crow0 = m0 + wm * 64 + quad * 4;
    const int ccol0 = n0 + wn * 64 + l16;
#pragma unroll
    for (int j = 0; j < 4; ++j) {
      const int col = ccol0 + j * 16;
      const float dpv = dp[col];
#pragma unroll
      for (int i = 0; i < 4; ++i)
#pragma unroll
        for (int p = 0; p < 4; ++p) {
          const int row = crow0 + i * 16 + p;
          out[(size_t)row * N + col] = acc[i][j][p] + dpv * (float)xb[(size_t)row * N + col];
        }
    }
  }
}

// ---------------- carry scan over chunks: PARALLEL Kogge-Stone, IN PLACE ------
// h_c = lamC * h_{c-1} + e_c (first-order linear recurrence over NC=512 chunks).
// Kogge-Stone: val[c] += lamC^s * val[c-s], s = 1..256 (9 LDS steps); span
// multiplier by repeated squaring. Grid: DH blocks x NC threads. In place:
// block h reads column 2h of chunk_carry (endpoints) then overwrites the same
// column with the EXCLUSIVE carries — no cross-block column sharing.
__global__ void k_scan_carry(float* __restrict__ chunk_carry,
                             const float* __restrict__ lamC_re,
                             const float* __restrict__ lamC_im,
                             float* __restrict__ out_final,
                             int interleave) {
  __shared__ float sr[NC], si[NC];
  const int h = blockIdx.x;            // complex channel 0..1023
  const int c = threadIdx.x;           // chunk 0..511
  f32x2 e = *(const f32x2*)(chunk_carry + (size_t)c * NH2 + 2 * h);
  float vr = e[0], vi = e[1];
  float pr = lamC_re[h], pi = lamC_im[h];   // lamC^(2^s)
#pragma unroll
  for (int s = 1; s < NC; s <<= 1) {
    sr[c] = vr; si[c] = vi;
    __syncthreads();
    if (c >= s) {
      const float ar = sr[c - s], ai = si[c - s];
      vr += pr * ar - pi * ai;
      vi += pr * ai + pi * ar;
    }
    __syncthreads();
    const float nr = pr * pr - pi * pi;
    const float ni = 2.f * pr * pi;
    pr = nr; pi = ni;
  }
  sr[c] = vr; si[c] = vi;
  __syncthreads();
  const float er = (c == 0) ? 0.f : sr[c - 1];
  const float ei = (c == 0) ? 0.f : si[c - 1];
  *(f32x2*)(chunk_carry + (size_t)c * NH2 + 2 * h) = f32x2{er, ei};
  if (c == NC - 1) {
    if (interleave) {
      *(f32x2*)(out_final + 2 * h) = f32x2{vr * INV_WSCALE, vi * INV_WSCALE};
    } else {
      out_final[h] = vr * INV_WSCALE;
    }
  }
}

// ---------------- apply: H over Bu in place (interleaved complex) ----------------
// Recurrence runs in the SCALED domain; stores unscale (x1/64) so H feeds GEMM2.
// LC=32: 1024 blocks (4/CU), 32-iter dependent chain.
__global__ void k_scan_apply(f16* __restrict__ Bu,
                             const float* __restrict__ lam_re,
                             const float* __restrict__ lam_im,
                             const float* __restrict__ carry_in) {
  const int colbase = (blockIdx.y * 256 + (int)threadIdx.x) * 4;  // 2 complex channels
  const int c = blockIdx.x;
  const int h0 = colbase >> 1;
  const float lr0 = lam_re[h0],     li0 = lam_im[h0];
  const float lr1 = lam_re[h0 + 1], li1 = lam_im[h0 + 1];
  f32x4 cv = *(const f32x4*)(carry_in + (size_t)c * NH2 + colbase);
  float hr0 = cv[0], hi0 = cv[1], hr1 = cv[2], hi1 = cv[3];
  f16* p = Bu + (size_t)c * LC * NH2 + colbase;
#pragma unroll 4
  for (int t = 0; t < LC; ++t) {
    f16x4 b = *(const f16x4*)(p);
    float nr0 = lr0 * hr0 - li0 * hi0 + (float)b[0];
    float ni0 = lr0 * hi0 + li0 * hr0 + (float)b[1];
    float nr1 = lr1 * hr1 - li1 * hi1 + (float)b[2];
    float ni1 = lr1 * hi1 + li1 * hr1 + (float)b[3];
    hr0 = nr0; hi0 = ni0; hr1 = nr1; hi1 = ni1;
    f16x4 wv;
    wv[0] = (f16)(hr0 * INV_WSCALE); wv[1] = (f16)(hi0 * INV_WSCALE);
    wv[2] = (f16)(hr1 * INV_WSCALE); wv[3] = (f16)(hi1 * INV_WSCALE);
    *(f16x4*)(p) = wv;
    p += NH2;
  }
}

// ---------------- launcher ----------------

extern "C" void kernel_launch(void* const* d_in, const int* in_sizes, int n_in,
                              void* d_out, int out_size, void* d_ws, size_t ws_size,
                              hipStream_t stream) {
  const float* inputs    = (const float*)d_in[0];
  const float* nu_log    = (const float*)d_in[1];
  const float* theta_log = (const float*)d_in[2];
  const float* gamma_log = (const float*)d_in[3];
  const float* B_re      = (const float*)d_in[4];
  const float* B_im      = (const float*)d_in[5];
  const float* C_re      = (const float*)d_in[6];
  const float* C_im      = (const float*)d_in[7];
  const float* Dp        = (const float*)d_in[8];

  char* ws = (char*)d_ws;
  float* lam_re     = (float*)(ws + 0);
  float* lam_im     = (float*)(ws + 4096);
  float* lamC_re    = (float*)(ws + 8192);
  float* lamC_im    = (float*)(ws + 12288);
  float* chunk_carry= (float*)(ws + 65536);                    //  4 MB [NC][NH2]
  f16*   Wcat       = (f16*)  (ws + 65536 + (4u << 20));       //  4 MB
  f16*   Ccat       = (f16*)  (ws + 65536 + (8u << 20));       //  4 MB
  f16*   Xb         = (f16*)  (ws + 65536 + (12u << 20));      // 32 MB
  f16*   Bu         = (f16*)  (ws + 65536 + (44u << 20));      // 64 MB (H in place)

  int interleave = 1;
  int state_floats = 2048;
  if (out_size == 1024 + L_SEQ * DM) { interleave = 0; state_floats = 1024; }

  float* out_state = (float*)d_out;
  float* out_y     = (float*)d_out + state_floats;   // [L, DM] f32

  k_prep_all<<<dim3(NB_CAST + 2 * NB_W + 4), dim3(256), 0, stream>>>(
      inputs, Xb, B_re, B_im, gamma_log, Wcat, C_re, C_im, Ccat,
      nu_log, theta_log, lam_re, lam_im, lamC_re, lamC_im);

  // GEMM1: Bu[L, NH2] = Xb[L, DM] @ Wcat[NH2, DM]^T, + local chunk scan -> chunk_carry
  k_gemm<0><<<dim3(L_SEQ / 128, NH2 / 128), dim3(256), 0, stream>>>(
      Xb, Wcat, (void*)Bu, nullptr, nullptr, lam_re, lam_im, chunk_carry, DM, NH2);

  // carry scan in place: endpoints -> exclusive carries (+ final state out)
  k_scan_carry<<<dim3(DH), dim3(NC), 0, stream>>>(chunk_carry, lamC_re, lamC_im,
                                                  out_state, interleave);
  k_scan_apply<<<dim3(NC, 2), dim3(256), 0, stream>>>(Bu, lam_re, lam_im, chunk_carry);

  // GEMM2: out_y = H[L, NH2] @ Ccat[DM, NH2]^T + Dp*Xb  (Xb passed as x, f16)
  k_gemm<1><<<dim3(L_SEQ / 128, DM / 128), dim3(256), 0, stream>>>(
      Bu, Ccat, (void*)out_y, Xb, Dp, nullptr, nullptr, nullptr, NH2, DM);

  (void)in_sizes; (void)n_in; (void)ws_size;
}